// Round 4
// baseline (241.454 us; speedup 1.0000x reference)
//
#include <hip/hip_runtime.h>
#include <hip/hip_bf16.h>
#include <hip/hip_cooperative_groups.h>

namespace cg = cooperative_groups;

#define D_IN   128
#define D_OUT  64
#define CAP    64          // per-node bucket capacity; overflow handled exactly
#define MAX_USHORT_NODES 65536
#define BIN_SHIFT 6        // 64 node ids per bin
#define MAX_BINS  1024
#define BIN_CAP   4096     // scratch slots per bin (expected ~1023; exact via ovfA)
#define FUSED_BLOCKS 256   // == CU count; co-resident by construction
#define P1B 64             // bin1 blocks inside fused grid (rest do proj)
#define FAT_THREADS 512

using frag_ab = __attribute__((ext_vector_type(8))) short;  // 8 bf16
using frag_cd = __attribute__((ext_vector_type(4))) float;  // 4 fp32

static __device__ __forceinline__ short f2bf(float f) {
    union { float f; unsigned u; } v; v.f = f;
    unsigned r = v.u + 0x7FFFu + ((v.u >> 16) & 1u);   // RNE truncate to bf16
    return (short)(r >> 16);
}
static __device__ __forceinline__ float bflo(unsigned w) {
    union { unsigned u; float f; } v; v.u = w << 16; return v.f;
}
static __device__ __forceinline__ float bfhi(unsigned w) {
    union { unsigned u; float f; } v; v.u = w & 0xFFFF0000u; return v.f;
}

// ---------------------------------------------------------------------------
// Device helpers shared by fused + fallback kernels.
// ---------------------------------------------------------------------------
static __device__ __forceinline__ void proj_body(
        const float* __restrict__ x, const float* __restrict__ W,
        const float* __restrict__ bvec, unsigned short* __restrict__ h,
        int n_nodes, int wid, int nwaves, int lane) {
    const int m    = lane & 15;
    const int quad = lane >> 4;

    frag_ab Bf[4][4];
#pragma unroll
    for (int kk = 0; kk < 4; ++kk) {
#pragma unroll
        for (int nt = 0; nt < 4; ++nt) {
            const float* wp = W + (size_t)(nt * 16 + m) * D_IN + kk * 32 + quad * 8;
            const float4 w0 = *(const float4*)wp;
            const float4 w1 = *(const float4*)(wp + 4);
            frag_ab f;
            f[0] = f2bf(w0.x); f[1] = f2bf(w0.y); f[2] = f2bf(w0.z); f[3] = f2bf(w0.w);
            f[4] = f2bf(w1.x); f[5] = f2bf(w1.y); f[6] = f2bf(w1.z); f[7] = f2bf(w1.w);
            Bf[kk][nt] = f;
        }
    }
    float bb[4];
#pragma unroll
    for (int nt = 0; nt < 4; ++nt) bb[nt] = bvec[nt * 16 + m];

    const int ntiles = (n_nodes + 15) / 16;
    for (int tile = wid; tile < ntiles; tile += nwaves) {
        const int node_base = tile * 16;
        int arow = node_base + m;
        if (arow > n_nodes - 1) arow = n_nodes - 1;

        float4 xv[8];
        const float* xr = x + (size_t)arow * D_IN + quad * 8;
#pragma unroll
        for (int kk = 0; kk < 4; ++kk) {
            xv[2 * kk]     = *(const float4*)(xr + kk * 32);
            xv[2 * kk + 1] = *(const float4*)(xr + kk * 32 + 4);
        }

        frag_cd acc[4];
#pragma unroll
        for (int nt = 0; nt < 4; ++nt) {
            acc[nt][0] = bb[nt]; acc[nt][1] = bb[nt];
            acc[nt][2] = bb[nt]; acc[nt][3] = bb[nt];
        }
#pragma unroll
        for (int kk = 0; kk < 4; ++kk) {
            const float4 x0 = xv[2 * kk], x1 = xv[2 * kk + 1];
            frag_ab A;
            A[0] = f2bf(x0.x); A[1] = f2bf(x0.y); A[2] = f2bf(x0.z); A[3] = f2bf(x0.w);
            A[4] = f2bf(x1.x); A[5] = f2bf(x1.y); A[6] = f2bf(x1.z); A[7] = f2bf(x1.w);
#pragma unroll
            for (int nt = 0; nt < 4; ++nt)
                acc[nt] = __builtin_amdgcn_mfma_f32_16x16x32_bf16(A, Bf[kk][nt],
                                                                  acc[nt], 0, 0, 0);
        }
#pragma unroll
        for (int nt = 0; nt < 4; ++nt) {
#pragma unroll
            for (int r = 0; r < 4; ++r) {
                const int node = node_base + quad * 4 + r;
                if (node < n_nodes)
                    h[(size_t)node * D_OUT + nt * 16 + m] =
                        (unsigned short)f2bf(acc[nt][r]);
            }
        }
    }
}

// ---------------------------------------------------------------------------
// ONE cooperative kernel for the whole chain:
//   phase 0: zero cursor + ovf counters          (kills the memset dispatch)
//   phase 1: bin1 (blocks 0..P1B) || proj (rest) (complementary pipes)
//   phase 2: per-bin LDS bucket build + gather   (grid-strided over bins)
//   phase 3: overflow apply                      (normally zero work)
// grid = 256 blocks x 512 thr: __launch_bounds__(512) caps VGPR at 256 ->
// 8 waves/CU -> 1 block/CU minimum -> all 256 blocks co-resident. LDS 16.7KB.
// ---------------------------------------------------------------------------
__global__ __launch_bounds__(FAT_THREADS)
void fused_kernel(const float* __restrict__ x, const float* __restrict__ W,
                  const float* __restrict__ bvec, unsigned short* __restrict__ h,
                  const int* __restrict__ row, const int* __restrict__ col,
                  unsigned* __restrict__ scratch, int* __restrict__ cursor,
                  int* __restrict__ ovf_cnts, unsigned* __restrict__ ovfA_list,
                  unsigned* __restrict__ ovfB_list, int ovf_cap,
                  int* __restrict__ deg, float* __restrict__ out,
                  int n_nodes, int n_edges, int n_bins) {
    __shared__ int hist[MAX_BINS];
    __shared__ int base[MAX_BINS];
    __shared__ int ldeg[64];
    __shared__ unsigned short lbuck[64 * CAP];   // 8 KB

    cg::grid_group grid = cg::this_grid();
    const int tid  = (int)threadIdx.x;
    const int gtid = (int)(blockIdx.x * blockDim.x + threadIdx.x);
    const int gsz  = (int)(gridDim.x * blockDim.x);
    const uint2* h64 = (const uint2*)h;

    // ---- phase 0: zero cursor + counters ----
    for (int i = gtid; i < n_bins * 16; i += gsz) cursor[i] = 0;
    if (gtid == 0) { ovf_cnts[0] = 0; ovf_cnts[1] = 0; }
    grid.sync();

    // ---- phase 1: bin1 || proj ----
    if ((int)blockIdx.x < P1B) {
        const int per = (n_edges + P1B - 1) / P1B;
        const int e0 = (int)blockIdx.x * per;
        const int e1 = min(e0 + per, n_edges);

        for (int i = tid; i < n_bins; i += FAT_THREADS) hist[i] = 0;
        __syncthreads();
        for (int e = e0 + tid; e < e1; e += FAT_THREADS)
            atomicAdd(&hist[row[e] >> BIN_SHIFT], 1);
        __syncthreads();
        for (int i = tid; i < n_bins; i += FAT_THREADS) {
            const int hcnt = hist[i];
            base[i] = hcnt > 0 ? atomicAdd(&cursor[i * 16], hcnt) : 0;
            hist[i] = 0;
        }
        __syncthreads();
        for (int e = e0 + tid; e < e1; e += FAT_THREADS) {
            const int r = row[e];
            const int c = col[e];
            const int bn = r >> BIN_SHIFT;
            const int loc = atomicAdd(&hist[bn], 1);
            const int off = base[bn] + loc;
            if (off < BIN_CAP) {
                scratch[(size_t)bn * BIN_CAP + off] =
                    (unsigned)(r & 63) | ((unsigned)c << 6);
            } else {
                const int k = atomicAdd(&ovf_cnts[0], 1);
                if (k < ovf_cap) ovfA_list[k] = (unsigned)r | ((unsigned)c << 16);
            }
        }
    } else {
        const int lane = tid & 63;
        const int wid  = ((int)blockIdx.x - P1B) * (FAT_THREADS >> 6) + (tid >> 6);
        const int nwaves = ((int)gridDim.x - P1B) * (FAT_THREADS >> 6);
        proj_body(x, W, bvec, h, n_nodes, wid, nwaves, lane);
    }
    grid.sync();

    // ---- phase 2: per-bin bucket build + gather ----
    const int lane = tid & 63;
    const int q = lane >> 4;
    const int j = lane & 15;
    const int w = tid >> 6;
    int cA = ovf_cnts[0]; if (cA > ovf_cap) cA = ovf_cap;

    for (int bin = (int)blockIdx.x; bin < n_bins; bin += (int)gridDim.x) {
        __syncthreads();                      // protect lbuck/ldeg reuse
        if (tid < 64) ldeg[tid] = 0;
        __syncthreads();

        const int node0 = bin << BIN_SHIFT;
        int cnt = cursor[bin * 16]; if (cnt > BIN_CAP) cnt = BIN_CAP;

        for (int i = tid; i < cnt; i += FAT_THREADS) {
            const unsigned rec = scratch[(size_t)bin * BIN_CAP + i];
            const int rl = (int)(rec & 63u);
            const int s = atomicAdd(&ldeg[rl], 1);
            if (s < CAP) {
                lbuck[(rl << 6) + s] = (unsigned short)(rec >> 6);
            } else {
                const int k = atomicAdd(&ovf_cnts[1], 1);
                if (k < ovf_cap)
                    ovfB_list[k] = (unsigned)(node0 + rl) | ((rec >> 6) << 16);
            }
        }
        for (int i = tid; i < cA; i += FAT_THREADS) {
            const unsigned rec = ovfA_list[i];
            const int r = (int)(rec & 0xFFFFu);
            if ((r >> BIN_SHIFT) == bin) atomicAdd(&ldeg[r & 63], 1);
        }
        __syncthreads();

        if (tid < 64 && node0 + tid < n_nodes) deg[node0 + tid] = ldeg[tid];

        for (int r6 = w; r6 < 64; r6 += 8) {
            const int node = node0 + r6;
            if (node >= n_nodes) continue;
            const int d = ldeg[r6];
            const int dc = d < CAP ? d : CAP;
            const int ngr = (dc + 3) >> 2;
            const unsigned short* brow = &lbuck[r6 << 6];

            float a0 = 0.f, a1 = 0.f, a2 = 0.f, a3 = 0.f;
            float b0 = 0.f, b1 = 0.f, b2 = 0.f, b3 = 0.f;
            int g = 0;
            for (; g + 2 <= ngr; g += 2) {
                const int iA = (int)brow[4 * g + q];   // LDS broadcast per quarter
                const int iB = (int)brow[4 * g + 4 + q];
                uint2 wA = h64[(size_t)iA * 16 + j];
                uint2 wB = h64[(size_t)iB * 16 + j];
                if (4 * g + q >= dc)     { wA.x = 0u; wA.y = 0u; }
                if (4 * g + 4 + q >= dc) { wB.x = 0u; wB.y = 0u; }
                a0 += bflo(wA.x); a1 += bfhi(wA.x); a2 += bflo(wA.y); a3 += bfhi(wA.y);
                b0 += bflo(wB.x); b1 += bfhi(wB.x); b2 += bflo(wB.y); b3 += bfhi(wB.y);
            }
            for (; g < ngr; ++g) {
                const int iA = (int)brow[4 * g + q];
                uint2 wA = h64[(size_t)iA * 16 + j];
                if (4 * g + q >= dc) { wA.x = 0u; wA.y = 0u; }
                a0 += bflo(wA.x); a1 += bfhi(wA.x); a2 += bflo(wA.y); a3 += bfhi(wA.y);
            }
            a0 += b0; a1 += b1; a2 += b2; a3 += b3;
            a0 += __shfl_xor(a0, 16); a0 += __shfl_xor(a0, 32);
            a1 += __shfl_xor(a1, 16); a1 += __shfl_xor(a1, 32);
            a2 += __shfl_xor(a2, 16); a2 += __shfl_xor(a2, 32);
            a3 += __shfl_xor(a3, 16); a3 += __shfl_xor(a3, 32);
            if (q == 0) {
                const float inv = 1.0f / fmaxf((float)d, 1.0f);
                float4 o;
                o.x = a0 * inv; o.y = a1 * inv; o.z = a2 * inv; o.w = a3 * inv;
                *(float4*)(out + (size_t)node * D_OUT + j * 4) = o;
            }
        }
    }
    grid.sync();

    // ---- phase 3: overflow apply (normally zero work) ----
    cA = ovf_cnts[0]; if (cA > ovf_cap) cA = ovf_cap;
    int cB = ovf_cnts[1]; if (cB > ovf_cap) cB = ovf_cap;
    const long long n_tasks = (long long)(cA + cB) * D_OUT;
    for (long long t = gtid; t < n_tasks; t += gsz) {
        const int k = (int)(t >> 6);
        const int ln = (int)(t & 63);
        const unsigned rec = (k < cA) ? ovfA_list[k] : ovfB_list[k - cA];
        const int r = (int)(rec & 0xFFFFu);
        const int c = (int)(rec >> 16);
        union { unsigned u; float f; } v;
        v.u = ((unsigned)h[(size_t)c * D_OUT + ln]) << 16;
        atomicAdd(&out[(size_t)r * D_OUT + ln],
                  v.f / fmaxf((float)deg[r], 1.0f));
    }
}

// ---------------------------------------------------------------------------
// Fallback multi-launch kernels (used if cooperative launch is unavailable).
// Identical logic, split at the grid.sync() points.
// ---------------------------------------------------------------------------
#define P1_BLOCKS 256

__global__ __launch_bounds__(FAT_THREADS)
void proj_bin1_kernel(const float* __restrict__ x, const float* __restrict__ W,
                      const float* __restrict__ bvec, unsigned short* __restrict__ h,
                      const int* __restrict__ row, const int* __restrict__ col,
                      unsigned* __restrict__ scratch, int* __restrict__ cursor,
                      int* __restrict__ ovfA_cnt, unsigned* __restrict__ ovfA_list,
                      int ovfA_cap, int n_nodes, int n_edges, int n_bins) {
    __shared__ int hist[MAX_BINS];
    __shared__ int base[MAX_BINS];

    if ((int)blockIdx.x < P1_BLOCKS) {
        const int per = (n_edges + P1_BLOCKS - 1) / P1_BLOCKS;
        const int e0 = (int)blockIdx.x * per;
        const int e1 = min(e0 + per, n_edges);

        for (int i = threadIdx.x; i < n_bins; i += FAT_THREADS) hist[i] = 0;
        __syncthreads();
        for (int e = e0 + (int)threadIdx.x; e < e1; e += FAT_THREADS)
            atomicAdd(&hist[row[e] >> BIN_SHIFT], 1);
        __syncthreads();
        for (int i = threadIdx.x; i < n_bins; i += FAT_THREADS) {
            const int hcnt = hist[i];
            base[i] = hcnt > 0 ? atomicAdd(&cursor[i * 16], hcnt) : 0;
            hist[i] = 0;
        }
        __syncthreads();
        for (int e = e0 + (int)threadIdx.x; e < e1; e += FAT_THREADS) {
            const int r = row[e];
            const int c = col[e];
            const int bn = r >> BIN_SHIFT;
            const int loc = atomicAdd(&hist[bn], 1);
            const int off = base[bn] + loc;
            if (off < BIN_CAP) {
                scratch[(size_t)bn * BIN_CAP + off] =
                    (unsigned)(r & 63) | ((unsigned)c << 6);
            } else {
                const int k = atomicAdd(ovfA_cnt, 1);
                if (k < ovfA_cap) ovfA_list[k] = (unsigned)r | ((unsigned)c << 16);
            }
        }
        return;
    }
    const int lane = (int)threadIdx.x & 63;
    const int wid  = ((int)blockIdx.x - P1_BLOCKS) * (FAT_THREADS >> 6)
                   + ((int)threadIdx.x >> 6);
    const int nwaves = ((int)gridDim.x - P1_BLOCKS) * (FAT_THREADS >> 6);
    proj_body(x, W, bvec, h, n_nodes, wid, nwaves, lane);
}

__global__ __launch_bounds__(FAT_THREADS)
void bin_gather_kernel(const unsigned* __restrict__ scratch,
                       const int* __restrict__ cursor,
                       const uint2* __restrict__ h64,
                       int* __restrict__ deg,
                       const unsigned* __restrict__ ovfA_list,
                       const int* __restrict__ ovfA_cnt, int ovfA_cap,
                       int* __restrict__ ovfB_cnt, unsigned* __restrict__ ovfB_list,
                       int ovfB_cap,
                       float* __restrict__ out, int n_nodes) {
    __shared__ int ldeg[64];
    __shared__ unsigned short lbuck[64 * CAP];
    const int bin   = (int)blockIdx.x;
    const int node0 = bin << BIN_SHIFT;

    int cnt = cursor[bin * 16]; if (cnt > BIN_CAP) cnt = BIN_CAP;

    if (threadIdx.x < 64) ldeg[threadIdx.x] = 0;
    __syncthreads();

    for (int i = threadIdx.x; i < cnt; i += FAT_THREADS) {
        const unsigned rec = scratch[(size_t)bin * BIN_CAP + i];
        const int rl = (int)(rec & 63u);
        const int s = atomicAdd(&ldeg[rl], 1);
        if (s < CAP) {
            lbuck[(rl << 6) + s] = (unsigned short)(rec >> 6);
        } else {
            const int k = atomicAdd(ovfB_cnt, 1);
            if (k < ovfB_cap)
                ovfB_list[k] = (unsigned)(node0 + rl) | ((rec >> 6) << 16);
        }
    }
    int cA = *ovfA_cnt; if (cA > ovfA_cap) cA = ovfA_cap;
    for (int i = threadIdx.x; i < cA; i += FAT_THREADS) {
        const unsigned rec = ovfA_list[i];
        const int r = (int)(rec & 0xFFFFu);
        if ((r >> BIN_SHIFT) == bin) atomicAdd(&ldeg[r & 63], 1);
    }
    __syncthreads();

    if (threadIdx.x < 64 && node0 + (int)threadIdx.x < n_nodes)
        deg[node0 + threadIdx.x] = ldeg[threadIdx.x];

    const int lane = (int)threadIdx.x & 63;
    const int q = lane >> 4;
    const int j = lane & 15;
    const int w = (int)threadIdx.x >> 6;

    for (int r6 = w; r6 < 64; r6 += 8) {
        const int node = node0 + r6;
        if (node >= n_nodes) continue;
        const int d = ldeg[r6];
        const int dc = d < CAP ? d : CAP;
        const int ngr = (dc + 3) >> 2;
        const unsigned short* brow = &lbuck[r6 << 6];

        float a0 = 0.f, a1 = 0.f, a2 = 0.f, a3 = 0.f;
        float b0 = 0.f, b1 = 0.f, b2 = 0.f, b3 = 0.f;
        int g = 0;
        for (; g + 2 <= ngr; g += 2) {
            const int iA = (int)brow[4 * g + q];
            const int iB = (int)brow[4 * g + 4 + q];
            uint2 wA = h64[(size_t)iA * 16 + j];
            uint2 wB = h64[(size_t)iB * 16 + j];
            if (4 * g + q >= dc)     { wA.x = 0u; wA.y = 0u; }
            if (4 * g + 4 + q >= dc) { wB.x = 0u; wB.y = 0u; }
            a0 += bflo(wA.x); a1 += bfhi(wA.x); a2 += bflo(wA.y); a3 += bfhi(wA.y);
            b0 += bflo(wB.x); b1 += bfhi(wB.x); b2 += bflo(wB.y); b3 += bfhi(wB.y);
        }
        for (; g < ngr; ++g) {
            const int iA = (int)brow[4 * g + q];
            uint2 wA = h64[(size_t)iA * 16 + j];
            if (4 * g + q >= dc) { wA.x = 0u; wA.y = 0u; }
            a0 += bflo(wA.x); a1 += bfhi(wA.x); a2 += bflo(wA.y); a3 += bfhi(wA.y);
        }
        a0 += b0; a1 += b1; a2 += b2; a3 += b3;
        a0 += __shfl_xor(a0, 16); a0 += __shfl_xor(a0, 32);
        a1 += __shfl_xor(a1, 16); a1 += __shfl_xor(a1, 32);
        a2 += __shfl_xor(a2, 16); a2 += __shfl_xor(a2, 32);
        a3 += __shfl_xor(a3, 16); a3 += __shfl_xor(a3, 32);
        if (q == 0) {
            const float inv = 1.0f / fmaxf((float)d, 1.0f);
            float4 o;
            o.x = a0 * inv; o.y = a1 * inv; o.z = a2 * inv; o.w = a3 * inv;
            *(float4*)(out + (size_t)node * D_OUT + j * 4) = o;
        }
    }
}

__global__ void ovf_apply_kernel(const unsigned short* __restrict__ h,
                                 const int* __restrict__ deg,
                                 const unsigned* __restrict__ listA,
                                 const int* __restrict__ cntA_p, int capA,
                                 const unsigned* __restrict__ listB,
                                 const int* __restrict__ cntB_p, int capB,
                                 float* __restrict__ out) {
    int cA = *cntA_p; if (cA > capA) cA = capA;
    int cB = *cntB_p; if (cB > capB) cB = capB;
    const long long n_tasks = (long long)(cA + cB) * D_OUT;
    long long t = (long long)blockIdx.x * blockDim.x + threadIdx.x;
    const long long stride = (long long)gridDim.x * blockDim.x;
    for (; t < n_tasks; t += stride) {
        const int k = (int)(t >> 6);
        const int lane = (int)(t & 63);
        const unsigned rec = (k < cA) ? listA[k] : listB[k - cA];
        const int r = (int)(rec & 0xFFFFu);
        const int c = (int)(rec >> 16);
        union { unsigned u; float f; } v;
        v.u = ((unsigned)h[(size_t)c * D_OUT + lane]) << 16;
        atomicAdd(&out[(size_t)r * D_OUT + lane],
                  v.f / fmaxf((float)deg[r], 1.0f));
    }
}

// ---------------------------------------------------------------------------
// Last-resort path (ws too small or n_nodes > 65536): fp32 h + atomic scatter.
// ---------------------------------------------------------------------------
__global__ void proj_only_kernel(const float* __restrict__ x,
                                 const float* __restrict__ W,
                                 const float* __restrict__ bvec,
                                 float* __restrict__ h, int n_nodes) {
    const int lane = (int)threadIdx.x & 63;
    const int wave = (int)((blockIdx.x * blockDim.x + threadIdx.x) >> 6);
    const int nwaves = (int)((gridDim.x * blockDim.x) >> 6);
    const float bias = bvec[lane];
    for (int node = wave; node < n_nodes; node += nwaves) {
        const float* xr = &x[(size_t)node * D_IN];
        float acc = bias;
#pragma unroll
        for (int k = 0; k < D_IN; ++k) acc += xr[k] * W[lane * D_IN + k];
        h[(size_t)node * D_OUT + lane] = acc;
    }
}

__global__ void scatter_kernel(const float* __restrict__ h,
                               const int* __restrict__ row,
                               const int* __restrict__ col,
                               float* __restrict__ out,
                               int* __restrict__ deg,
                               long long n_tasks) {
    long long t = (long long)blockIdx.x * blockDim.x + threadIdx.x;
    const long long stride = (long long)gridDim.x * blockDim.x;
    for (; t < n_tasks; t += stride) {
        const int e = (int)(t >> 6);
        const int c = (int)(t & 63);
        atomicAdd(&out[(size_t)row[e] * D_OUT + c], h[(size_t)col[e] * D_OUT + c]);
        if (c == 0) atomicAdd(&deg[row[e]], 1);
    }
}

__global__ void div_kernel(float* __restrict__ out,
                           const int* __restrict__ deg, int n_total) {
    int t = blockIdx.x * blockDim.x + threadIdx.x;
    if (t < n_total) {
        out[t] *= 1.0f / fmaxf((float)deg[t >> 6], 1.0f);
    }
}

extern "C" void kernel_launch(void* const* d_in, const int* in_sizes, int n_in,
                              void* d_out, int out_size, void* d_ws, size_t ws_size,
                              hipStream_t stream) {
    const float* x   = (const float*)d_in[0];
    const float* W   = (const float*)d_in[1];
    const float* b   = (const float*)d_in[2];
    const int*   row = (const int*)d_in[3];
    const int*   col = (const int*)d_in[4];
    float* out = (float*)d_out;

    const int n_nodes = in_sizes[0] / D_IN;
    const int n_edges = in_sizes[3];
    const int n_bins  = (n_nodes + 63) >> BIN_SHIFT;

    // Workspace: h(bf16) | deg | [ovfA_cnt ovfB_cnt pad 256B] | cursor(padded)
    //            | ovfA_list | ovfB_list | scratch
    char* p = (char*)d_ws;
    unsigned short* h = (unsigned short*)p;
    p += (size_t)n_nodes * D_OUT * sizeof(unsigned short);
    int* deg = (int*)p;            p += (size_t)n_nodes * sizeof(int);
    int* ovf_cnts = (int*)p;       p += 256;                       // [0]=A, [1]=B
    int* cursor = (int*)p;         p += (size_t)MAX_BINS * 16 * sizeof(int);
    unsigned* ovfA_list = (unsigned*)p;  p += (size_t)n_edges * sizeof(unsigned);
    unsigned* ovfB_list = (unsigned*)p;  p += (size_t)n_edges * sizeof(unsigned);
    unsigned* scratch = (unsigned*)p;
    p += (size_t)n_bins * BIN_CAP * sizeof(unsigned);
    const size_t needed = (size_t)(p - (char*)d_ws);

    if (ws_size >= needed && n_nodes <= MAX_USHORT_NODES) {
        // ---- preferred: single cooperative dispatch ----
        int ovf_cap = n_edges;
        void* args[] = {
            (void*)&x, (void*)&W, (void*)&b, (void*)&h, (void*)&row, (void*)&col,
            (void*)&scratch, (void*)&cursor, (void*)&ovf_cnts, (void*)&ovfA_list,
            (void*)&ovfB_list, (void*)&ovf_cap, (void*)&deg, (void*)&out,
            (void*)&n_nodes, (void*)&n_edges, (void*)&n_bins
        };
        hipError_t err = hipLaunchCooperativeKernel(
            (const void*)fused_kernel, dim3(FUSED_BLOCKS), dim3(FAT_THREADS),
            args, 0, stream);
        if (err == hipSuccess) return;
        (void)hipGetLastError();   // clear; fall through to multi-launch path

        // ---- fallback: proven 4-dispatch chain ----
        hipMemsetAsync(ovf_cnts, 0, 256 + (size_t)n_bins * 16 * sizeof(int),
                       stream);
        const int ntiles = (n_nodes + 15) / 16;
        int proj_blocks = (ntiles + 15) / 16;
        if (proj_blocks < 1) proj_blocks = 1;
        proj_bin1_kernel<<<P1_BLOCKS + proj_blocks, FAT_THREADS, 0, stream>>>(
            x, W, b, h, row, col, scratch, cursor, &ovf_cnts[0], ovfA_list,
            n_edges, n_nodes, n_edges, n_bins);
        bin_gather_kernel<<<n_bins, FAT_THREADS, 0, stream>>>(
            scratch, cursor, (const uint2*)h, deg, ovfA_list, &ovf_cnts[0],
            n_edges, &ovf_cnts[1], ovfB_list, n_edges, out, n_nodes);
        ovf_apply_kernel<<<256, 256, 0, stream>>>(h, deg, ovfA_list,
                                                  &ovf_cnts[0], n_edges,
                                                  ovfB_list, &ovf_cnts[1],
                                                  n_edges, out);
    } else {
        // last resort: fp32 h + atomic scatter
        float* hf = (float*)d_ws;
        int* degf = (int*)((char*)d_ws + (size_t)n_nodes * D_OUT * sizeof(float));
        hipMemsetAsync(out, 0, (size_t)out_size * sizeof(float), stream);
        hipMemsetAsync(degf, 0, (size_t)n_nodes * sizeof(int), stream);
        proj_only_kernel<<<1024, 256, 0, stream>>>(x, W, b, hf, n_nodes);
        const long long n_tasks = (long long)n_edges * D_OUT;
        scatter_kernel<<<16384, 256, 0, stream>>>(hf, row, col, out, degf, n_tasks);
        const int n_total = n_nodes * D_OUT;
        div_kernel<<<(n_total + 255) / 256, 256, 0, stream>>>(out, degf, n_total);
    }
}

// Round 5
// 132.280 us; speedup vs baseline: 1.8253x; 1.8253x over previous
//
#include <hip/hip_runtime.h>
#include <hip/hip_bf16.h>

#define D_IN   128
#define D_OUT  64
#define CAP    64          // per-node bucket capacity; overflow handled exactly
#define MAX_USHORT_NODES 65536
#define BIN_SHIFT 8        // 256 node ids per bin
#define MAX_BINS  256
#define SEG_CAP   64       // per (pass1-block, bin) scratch quota (exp ~16)
#define OVFB_CAP  16384    // worst case per gather block = 256*SEG_CAP
#define P1_BLOCKS 256
#define SPLIT 4            // gather blocks per bin (64 nodes each)
#define FAT_THREADS 512

using frag_ab = __attribute__((ext_vector_type(8))) short;  // 8 bf16
using frag_cd = __attribute__((ext_vector_type(4))) float;  // 4 fp32

static __device__ __forceinline__ short f2bf(float f) {
    union { float f; unsigned u; } v; v.f = f;
    unsigned r = v.u + 0x7FFFu + ((v.u >> 16) & 1u);   // RNE truncate to bf16
    return (short)(r >> 16);
}
static __device__ __forceinline__ float bflo(unsigned w) {
    union { unsigned u; float f; } v; v.u = w << 16; return v.f;
}
static __device__ __forceinline__ float bfhi(unsigned w) {
    union { unsigned u; float f; } v; v.u = w & 0xFFFF0000u; return v.f;
}

// ---------------------------------------------------------------------------
// Fat kernel: blocks [0, P1_BLOCKS) run single-pass binning into DETERMINISTIC
// per-(block,bin) scratch segments (no cursor, no global atomics, no memset
// dependency); blocks [P1_BLOCKS, ...) run the MFMA projection. All per-block
// outputs (counts, ovfA_cnts) are written unconditionally, so the poisoned
// workspace never needs pre-zeroing.
// Record pack: (r & 255) | c << 8.
// ---------------------------------------------------------------------------
__global__ __launch_bounds__(FAT_THREADS)
void proj_bin1_kernel(const float* __restrict__ x,
                      const float* __restrict__ W,
                      const float* __restrict__ bvec,
                      unsigned short* __restrict__ h,
                      const int* __restrict__ row, const int* __restrict__ col,
                      unsigned* __restrict__ scratch, int* __restrict__ counts,
                      int* __restrict__ ovfA_cnts, unsigned* __restrict__ ovfA_list,
                      int per_blkA, int n_nodes, int n_edges, int n_bins) {
    __shared__ int hist[MAX_BINS];
    __shared__ int lovf;

    if ((int)blockIdx.x < P1_BLOCKS) {
        // ---- single-pass binning ----
        const int blk = (int)blockIdx.x;
        const int per = (n_edges + P1_BLOCKS - 1) / P1_BLOCKS;
        const int e0 = blk * per;
        const int e1 = min(e0 + per, n_edges);

        for (int i = threadIdx.x; i < n_bins; i += FAT_THREADS) hist[i] = 0;
        if (threadIdx.x == 0) lovf = 0;
        __syncthreads();
        for (int e = e0 + (int)threadIdx.x; e < e1; e += FAT_THREADS) {
            const int r = row[e];
            const int c = col[e];
            const int bn = r >> BIN_SHIFT;
            const int loc = atomicAdd(&hist[bn], 1);
            if (loc < SEG_CAP) {
                scratch[((size_t)bn * P1_BLOCKS + blk) * SEG_CAP + loc] =
                    (unsigned)(r & 255) | ((unsigned)c << 8);
            } else {
                const int k = atomicAdd(&lovf, 1);
                if (k < per_blkA)
                    ovfA_list[(size_t)blk * per_blkA + k] =
                        (unsigned)r | ((unsigned)c << 16);
            }
        }
        __syncthreads();
        for (int i = threadIdx.x; i < n_bins; i += FAT_THREADS)
            counts[i * P1_BLOCKS + blk] = min(hist[i], SEG_CAP);
        if (threadIdx.x == 0) ovfA_cnts[blk] = min(lovf, per_blkA);
        return;
    }

    // ---- projection: wave = 16-node tile, grid-stride over proj blocks ----
    const int lane = (int)threadIdx.x & 63;
    const int wid  = ((int)blockIdx.x - P1_BLOCKS) * (FAT_THREADS >> 6)
                   + ((int)threadIdx.x >> 6);
    const int nwaves = ((int)gridDim.x - P1_BLOCKS) * (FAT_THREADS >> 6);
    const int m    = lane & 15;
    const int quad = lane >> 4;

    frag_ab Bf[4][4];
#pragma unroll
    for (int kk = 0; kk < 4; ++kk) {
#pragma unroll
        for (int nt = 0; nt < 4; ++nt) {
            const float* wp = W + (size_t)(nt * 16 + m) * D_IN + kk * 32 + quad * 8;
            const float4 w0 = *(const float4*)wp;
            const float4 w1 = *(const float4*)(wp + 4);
            frag_ab f;
            f[0] = f2bf(w0.x); f[1] = f2bf(w0.y); f[2] = f2bf(w0.z); f[3] = f2bf(w0.w);
            f[4] = f2bf(w1.x); f[5] = f2bf(w1.y); f[6] = f2bf(w1.z); f[7] = f2bf(w1.w);
            Bf[kk][nt] = f;
        }
    }
    float bb[4];
#pragma unroll
    for (int nt = 0; nt < 4; ++nt) bb[nt] = bvec[nt * 16 + m];

    const int ntiles = (n_nodes + 15) / 16;
    for (int tile = wid; tile < ntiles; tile += nwaves) {
        const int node_base = tile * 16;
        int arow = node_base + m;
        if (arow > n_nodes - 1) arow = n_nodes - 1;

        float4 xv[8];
        const float* xr = x + (size_t)arow * D_IN + quad * 8;
#pragma unroll
        for (int kk = 0; kk < 4; ++kk) {
            xv[2 * kk]     = *(const float4*)(xr + kk * 32);
            xv[2 * kk + 1] = *(const float4*)(xr + kk * 32 + 4);
        }

        frag_cd acc[4];
#pragma unroll
        for (int nt = 0; nt < 4; ++nt) {
            acc[nt][0] = bb[nt]; acc[nt][1] = bb[nt];
            acc[nt][2] = bb[nt]; acc[nt][3] = bb[nt];
        }
#pragma unroll
        for (int kk = 0; kk < 4; ++kk) {
            const float4 x0 = xv[2 * kk], x1 = xv[2 * kk + 1];
            frag_ab A;
            A[0] = f2bf(x0.x); A[1] = f2bf(x0.y); A[2] = f2bf(x0.z); A[3] = f2bf(x0.w);
            A[4] = f2bf(x1.x); A[5] = f2bf(x1.y); A[6] = f2bf(x1.z); A[7] = f2bf(x1.w);
#pragma unroll
            for (int nt = 0; nt < 4; ++nt)
                acc[nt] = __builtin_amdgcn_mfma_f32_16x16x32_bf16(A, Bf[kk][nt],
                                                                  acc[nt], 0, 0, 0);
        }
#pragma unroll
        for (int nt = 0; nt < 4; ++nt) {
#pragma unroll
            for (int r = 0; r < 4; ++r) {
                const int node = node_base + quad * 4 + r;
                if (node < n_nodes)
                    h[(size_t)node * D_OUT + nt * 16 + m] =
                        (unsigned short)f2bf(acc[nt][r]);
            }
        }
    }
}

// ---------------------------------------------------------------------------
// Fused bucket-build + degfix + gather. Block = (bin, slice of 64 nodes).
// Segment counts prefetched to LDS (one coalesced read), then each wave scans
// its segments (lane < cnt reads one record). LDS bucket rows, quarter-wave
// gather with uint2 h loads (L2-warm), shfl_xor reduce, fused mean.
// ovfB is block-private (non-atomic count), always written.
// ---------------------------------------------------------------------------
__global__ __launch_bounds__(FAT_THREADS)
void bin_gather_kernel(const unsigned* __restrict__ scratch,
                       const int* __restrict__ counts,
                       const uint2* __restrict__ h64,
                       int* __restrict__ deg,
                       const unsigned* __restrict__ ovfA_list,
                       const int* __restrict__ ovfA_cnts, int per_blkA,
                       int* __restrict__ ovfB_cnts, unsigned* __restrict__ ovfB_list,
                       float* __restrict__ out, int n_nodes) {
    __shared__ int ldeg[64];
    __shared__ unsigned short lbuck[64 * CAP];   // 8 KB
    __shared__ int scnt[P1_BLOCKS];              // 1 KB
    __shared__ int lovfB;
    __shared__ int anyA;

    const int g     = (int)blockIdx.x;
    const int bin   = g >> 2;
    const int slice = g & (SPLIT - 1);
    const int node0 = (bin << BIN_SHIFT) + (slice << 6);
    const int gslice = node0 >> 6;
    const int tid = (int)threadIdx.x;
    const int lane = tid & 63;
    const int w = tid >> 6;                      // wave 0..7

    if (tid < 64) ldeg[tid] = 0;
    if (tid == 0) { lovfB = 0; anyA = 0; }
    __syncthreads();

    // prefetch segment counts (coalesced) + ovfA fast-path flag
    for (int i = tid; i < P1_BLOCKS; i += FAT_THREADS)
        scnt[i] = counts[bin * P1_BLOCKS + i];
    if (tid < P1_BLOCKS && ovfA_cnts[tid] > 0) anyA = 1;
    __syncthreads();

    // scan segments: wave w handles segs w, w+8, ...; lane reads one record
    for (int seg = w; seg < P1_BLOCKS; seg += 8) {
        const int cnt = scnt[seg];
        if (lane < cnt) {
            const unsigned rec =
                scratch[((size_t)bin * P1_BLOCKS + seg) * SEG_CAP + lane];
            const int rl = (int)(rec & 255u);
            if ((rl >> 6) == slice) {
                const int r6 = rl & 63;
                const int s = atomicAdd(&ldeg[r6], 1);
                if (s < CAP) {
                    lbuck[(r6 << 6) + s] = (unsigned short)(rec >> 8);
                } else {
                    const int k = atomicAdd(&lovfB, 1);
                    if (k < OVFB_CAP)
                        ovfB_list[(size_t)g * OVFB_CAP + k] =
                            (unsigned)(node0 + r6) | ((rec >> 8) << 16);
                }
            }
        }
    }
    // fold pass1-overflow edges into deg (fast path: zero work)
    if (anyA) {
        for (int blk = 0; blk < P1_BLOCKS; ++blk) {
            int cA = ovfA_cnts[blk]; if (cA > per_blkA) cA = per_blkA;
            for (int i = tid; i < cA; i += FAT_THREADS) {
                const unsigned rec = ovfA_list[(size_t)blk * per_blkA + i];
                const int r = (int)(rec & 0xFFFFu);
                if ((r >> 6) == gslice) atomicAdd(&ldeg[r & 63], 1);
            }
        }
    }
    __syncthreads();

    if (tid == 0) ovfB_cnts[g] = min(lovfB, OVFB_CAP);
    if (tid < 64 && node0 + tid < n_nodes) deg[node0 + tid] = ldeg[tid];

    // gather straight from LDS buckets
    const int q = lane >> 4;
    const int j = lane & 15;
    for (int r6 = w; r6 < 64; r6 += 8) {
        const int node = node0 + r6;
        if (node >= n_nodes) continue;
        const int d = ldeg[r6];
        const int dc = d < CAP ? d : CAP;
        const int ngr = (dc + 3) >> 2;
        const unsigned short* brow = &lbuck[r6 << 6];

        float a0 = 0.f, a1 = 0.f, a2 = 0.f, a3 = 0.f;
        float b0 = 0.f, b1 = 0.f, b2 = 0.f, b3 = 0.f;
        int g2 = 0;
        for (; g2 + 2 <= ngr; g2 += 2) {
            const int iA = (int)brow[4 * g2 + q];     // LDS broadcast per quarter
            const int iB = (int)brow[4 * g2 + 4 + q];
            uint2 wA = h64[(size_t)iA * 16 + j];
            uint2 wB = h64[(size_t)iB * 16 + j];
            if (4 * g2 + q >= dc)     { wA.x = 0u; wA.y = 0u; }
            if (4 * g2 + 4 + q >= dc) { wB.x = 0u; wB.y = 0u; }
            a0 += bflo(wA.x); a1 += bfhi(wA.x); a2 += bflo(wA.y); a3 += bfhi(wA.y);
            b0 += bflo(wB.x); b1 += bfhi(wB.x); b2 += bflo(wB.y); b3 += bfhi(wB.y);
        }
        for (; g2 < ngr; ++g2) {
            const int iA = (int)brow[4 * g2 + q];
            uint2 wA = h64[(size_t)iA * 16 + j];
            if (4 * g2 + q >= dc) { wA.x = 0u; wA.y = 0u; }
            a0 += bflo(wA.x); a1 += bfhi(wA.x); a2 += bflo(wA.y); a3 += bfhi(wA.y);
        }
        a0 += b0; a1 += b1; a2 += b2; a3 += b3;
        a0 += __shfl_xor(a0, 16); a0 += __shfl_xor(a0, 32);
        a1 += __shfl_xor(a1, 16); a1 += __shfl_xor(a1, 32);
        a2 += __shfl_xor(a2, 16); a2 += __shfl_xor(a2, 32);
        a3 += __shfl_xor(a3, 16); a3 += __shfl_xor(a3, 32);
        if (q == 0) {
            const float inv = 1.0f / fmaxf((float)d, 1.0f);
            float4 o;
            o.x = a0 * inv; o.y = a1 * inv; o.z = a2 * inv; o.w = a3 * inv;
            *(float4*)(out + (size_t)node * D_OUT + j * 4) = o;
        }
    }
}

// ---------------------------------------------------------------------------
// Overflow apply (fast path: every count is zero). Grid-strides over the
// per-block A lists and per-gather-block B lists.
// ---------------------------------------------------------------------------
__global__ void ovf_apply_kernel(const unsigned short* __restrict__ h,
                                 const int* __restrict__ deg,
                                 const unsigned* __restrict__ ovfA_list,
                                 const int* __restrict__ ovfA_cnts, int per_blkA,
                                 int nA,
                                 const unsigned* __restrict__ ovfB_list,
                                 const int* __restrict__ ovfB_cnts, int nB,
                                 float* __restrict__ out) {
    for (int lst = (int)blockIdx.x; lst < nA + nB; lst += (int)gridDim.x) {
        const bool isA = lst < nA;
        int cnt = isA ? ovfA_cnts[lst] : ovfB_cnts[lst - nA];
        const int cap = isA ? per_blkA : OVFB_CAP;
        if (cnt > cap) cnt = cap;
        if (cnt <= 0) continue;
        const unsigned* list = isA ? ovfA_list + (size_t)lst * per_blkA
                                   : ovfB_list + (size_t)(lst - nA) * OVFB_CAP;
        const long long n_tasks = (long long)cnt * D_OUT;
        for (long long t = threadIdx.x; t < n_tasks; t += blockDim.x) {
            const int k = (int)(t >> 6);
            const int ln = (int)(t & 63);
            const unsigned rec = list[k];
            const int r = (int)(rec & 0xFFFFu);
            const int c = (int)(rec >> 16);
            union { unsigned u; float f; } v;
            v.u = ((unsigned)h[(size_t)c * D_OUT + ln]) << 16;
            atomicAdd(&out[(size_t)r * D_OUT + ln],
                      v.f / fmaxf((float)deg[r], 1.0f));
        }
    }
}

// ---------------------------------------------------------------------------
// Last-resort path (ws too small or n_nodes > 65536): fp32 h + atomic scatter.
// ---------------------------------------------------------------------------
__global__ void proj_only_kernel(const float* __restrict__ x,
                                 const float* __restrict__ W,
                                 const float* __restrict__ bvec,
                                 float* __restrict__ h, int n_nodes) {
    const int lane = (int)threadIdx.x & 63;
    const int wave = (int)((blockIdx.x * blockDim.x + threadIdx.x) >> 6);
    const int nwaves = (int)((gridDim.x * blockDim.x) >> 6);
    const float bias = bvec[lane];
    for (int node = wave; node < n_nodes; node += nwaves) {
        const float* xr = &x[(size_t)node * D_IN];
        float acc = bias;
#pragma unroll
        for (int k = 0; k < D_IN; ++k) acc += xr[k] * W[lane * D_IN + k];
        h[(size_t)node * D_OUT + lane] = acc;
    }
}

__global__ void scatter_kernel(const float* __restrict__ h,
                               const int* __restrict__ row,
                               const int* __restrict__ col,
                               float* __restrict__ out,
                               int* __restrict__ deg,
                               long long n_tasks) {
    long long t = (long long)blockIdx.x * blockDim.x + threadIdx.x;
    const long long stride = (long long)gridDim.x * blockDim.x;
    for (; t < n_tasks; t += stride) {
        const int e = (int)(t >> 6);
        const int c = (int)(t & 63);
        atomicAdd(&out[(size_t)row[e] * D_OUT + c], h[(size_t)col[e] * D_OUT + c]);
        if (c == 0) atomicAdd(&deg[row[e]], 1);
    }
}

__global__ void div_kernel(float* __restrict__ out,
                           const int* __restrict__ deg, int n_total) {
    int t = blockIdx.x * blockDim.x + threadIdx.x;
    if (t < n_total) {
        out[t] *= 1.0f / fmaxf((float)deg[t >> 6], 1.0f);
    }
}

extern "C" void kernel_launch(void* const* d_in, const int* in_sizes, int n_in,
                              void* d_out, int out_size, void* d_ws, size_t ws_size,
                              hipStream_t stream) {
    const float* x   = (const float*)d_in[0];
    const float* W   = (const float*)d_in[1];
    const float* b   = (const float*)d_in[2];
    const int*   row = (const int*)d_in[3];
    const int*   col = (const int*)d_in[4];
    float* out = (float*)d_out;

    const int n_nodes = in_sizes[0] / D_IN;
    const int n_edges = in_sizes[3];
    const int n_bins  = (n_nodes + 255) >> BIN_SHIFT;
    const int n_gb    = n_bins * SPLIT;
    const int per_blkA = (n_edges + P1_BLOCKS - 1) / P1_BLOCKS;

    // Workspace: h(bf16) | deg | ovfA_cnts | ovfB_cnts | counts
    //            | ovfA_list | ovfB_list | scratch      (NO memset needed:
    // every counter/count is written unconditionally by its owning block)
    char* p = (char*)d_ws;
    unsigned short* h = (unsigned short*)p;
    p += (size_t)n_nodes * D_OUT * sizeof(unsigned short);
    int* deg = (int*)p;         p += (size_t)n_nodes * sizeof(int);
    int* ovfA_cnts = (int*)p;   p += (size_t)P1_BLOCKS * sizeof(int);
    int* ovfB_cnts = (int*)p;   p += (size_t)n_gb * sizeof(int);
    int* counts = (int*)p;      p += (size_t)n_bins * P1_BLOCKS * sizeof(int);
    unsigned* ovfA_list = (unsigned*)p;
    p += (size_t)P1_BLOCKS * per_blkA * sizeof(unsigned);
    unsigned* ovfB_list = (unsigned*)p;
    p += (size_t)n_gb * OVFB_CAP * sizeof(unsigned);
    unsigned* scratch = (unsigned*)p;
    p += (size_t)n_bins * P1_BLOCKS * SEG_CAP * sizeof(unsigned);
    const size_t needed = (size_t)(p - (char*)d_ws);

    if (ws_size >= needed && n_nodes <= MAX_USHORT_NODES) {
        // 1) projection || single-pass binning (no memset, no global atomics)
        const int ntiles = (n_nodes + 15) / 16;
        int proj_blocks = (ntiles + 15) / 16;     // 8 waves/block, 2 tiles/wave
        if (proj_blocks < 1) proj_blocks = 1;
        proj_bin1_kernel<<<P1_BLOCKS + proj_blocks, FAT_THREADS, 0, stream>>>(
            x, W, b, h, row, col, scratch, counts, ovfA_cnts, ovfA_list,
            per_blkA, n_nodes, n_edges, n_bins);

        // 2) fused bucket-build + degfix + gather
        bin_gather_kernel<<<n_gb, FAT_THREADS, 0, stream>>>(
            scratch, counts, (const uint2*)h, deg, ovfA_list, ovfA_cnts,
            per_blkA, ovfB_cnts, ovfB_list, out, n_nodes);

        // 3) overflow contributions (zero work in practice)
        ovf_apply_kernel<<<256, 256, 0, stream>>>(h, deg, ovfA_list, ovfA_cnts,
                                                  per_blkA, P1_BLOCKS,
                                                  ovfB_list, ovfB_cnts, n_gb,
                                                  out);
    } else {
        // last resort: fp32 h + atomic scatter
        float* hf = (float*)d_ws;
        int* degf = (int*)((char*)d_ws + (size_t)n_nodes * D_OUT * sizeof(float));
        hipMemsetAsync(out, 0, (size_t)out_size * sizeof(float), stream);
        hipMemsetAsync(degf, 0, (size_t)n_nodes * sizeof(int), stream);
        proj_only_kernel<<<1024, 256, 0, stream>>>(x, W, b, hf, n_nodes);
        const long long n_tasks = (long long)n_edges * D_OUT;
        scatter_kernel<<<16384, 256, 0, stream>>>(hf, row, col, out, degf, n_tasks);
        const int n_total = n_nodes * D_OUT;
        div_kernel<<<(n_total + 255) / 256, 256, 0, stream>>>(out, degf, n_total);
    }
}

// Round 6
// 121.715 us; speedup vs baseline: 1.9838x; 1.0868x over previous
//
#include <hip/hip_runtime.h>
#include <hip/hip_bf16.h>

#define D_IN   128
#define D_OUT  64
#define CAP    64          // per-node bucket capacity; overflow exact via facc
#define MAX_USHORT_NODES 65536
#define BIN_SHIFT 8        // 256 node ids per bin
#define MAX_BINS  256
#define BIN_CAP   8192     // scratch slots per bin (expected ~4082; exact via ovfA)
#define P1_BLOCKS 256
#define FAT_THREADS 512
#define SPLIT 4            // bin_gather blocks per bin (64 nodes each)
#define SPLIT_SHIFT 2

using frag_ab = __attribute__((ext_vector_type(8))) short;  // 8 bf16
using frag_cd = __attribute__((ext_vector_type(4))) float;  // 4 fp32

static __device__ __forceinline__ short f2bf(float f) {
    union { float f; unsigned u; } v; v.f = f;
    unsigned r = v.u + 0x7FFFu + ((v.u >> 16) & 1u);   // RNE truncate to bf16
    return (short)(r >> 16);
}
static __device__ __forceinline__ float bflo(unsigned w) {
    union { unsigned u; float f; } v; v.u = w << 16; return v.f;
}
static __device__ __forceinline__ float bfhi(unsigned w) {
    union { unsigned u; float f; } v; v.u = w & 0xFFFF0000u; return v.f;
}

// exact streaming accumulate of h-row c into facc row r6 (overflow path;
// zero-cost when no node exceeds CAP)
static __device__ __forceinline__ void facc_accum(float* facc,
                                                  const uint2* __restrict__ h64,
                                                  int r6, int c) {
    const uint2* hr = h64 + (size_t)c * 16;
#pragma unroll 4
    for (int t = 0; t < 16; ++t) {
        const uint2 wv = hr[t];
        atomicAdd(&facc[(r6 << 6) + t * 4 + 0], bflo(wv.x));
        atomicAdd(&facc[(r6 << 6) + t * 4 + 1], bfhi(wv.x));
        atomicAdd(&facc[(r6 << 6) + t * 4 + 2], bflo(wv.y));
        atomicAdd(&facc[(r6 << 6) + t * 4 + 3], bfhi(wv.y));
    }
}

// ---------------------------------------------------------------------------
// Fat kernel (identical to round-1 best): blocks [0, P1_BLOCKS) run binpass1
// (per-block LDS histogram -> one global atomic per (block,bin) -> packed
// scatter into bin scratch); blocks [P1_BLOCKS, ...) run the MFMA projection.
// Record pack: (r & 255) | c << 8.
// ---------------------------------------------------------------------------
__global__ __launch_bounds__(FAT_THREADS)
void proj_bin1_kernel(const float* __restrict__ x,
                      const float* __restrict__ W,
                      const float* __restrict__ bvec,
                      unsigned short* __restrict__ h,
                      const int* __restrict__ row, const int* __restrict__ col,
                      unsigned* __restrict__ scratch, int* __restrict__ cursor,
                      int* __restrict__ ovfA_cnt, unsigned* __restrict__ ovfA_list,
                      int ovfA_cap, int n_nodes, int n_edges, int n_bins) {
    __shared__ int hist[MAX_BINS];
    __shared__ int base[MAX_BINS];

    if ((int)blockIdx.x < P1_BLOCKS) {
        // ---- binpass1 ----
        const int per = (n_edges + P1_BLOCKS - 1) / P1_BLOCKS;
        const int e0 = (int)blockIdx.x * per;
        const int e1 = min(e0 + per, n_edges);

        for (int i = threadIdx.x; i < n_bins; i += FAT_THREADS) hist[i] = 0;
        __syncthreads();
        for (int e = e0 + (int)threadIdx.x; e < e1; e += FAT_THREADS)
            atomicAdd(&hist[row[e] >> BIN_SHIFT], 1);
        __syncthreads();
        for (int i = threadIdx.x; i < n_bins; i += FAT_THREADS) {
            const int hcnt = hist[i];
            base[i] = hcnt > 0 ? atomicAdd(&cursor[i * 16], hcnt) : 0;
            hist[i] = 0;
        }
        __syncthreads();
        for (int e = e0 + (int)threadIdx.x; e < e1; e += FAT_THREADS) {
            const int r = row[e];
            const int c = col[e];
            const int bn = r >> BIN_SHIFT;
            const int loc = atomicAdd(&hist[bn], 1);
            const int off = base[bn] + loc;
            if (off < BIN_CAP) {
                scratch[(size_t)bn * BIN_CAP + off] =
                    (unsigned)(r & 255) | ((unsigned)c << 8);
            } else {
                const int k = atomicAdd(ovfA_cnt, 1);
                if (k < ovfA_cap) ovfA_list[k] = (unsigned)r | ((unsigned)c << 16);
            }
        }
        return;
    }

    // ---- projection: wave = 16-node tile, grid-stride over proj blocks ----
    const int lane = (int)threadIdx.x & 63;
    const int wid  = ((int)blockIdx.x - P1_BLOCKS) * (FAT_THREADS >> 6)
                   + ((int)threadIdx.x >> 6);
    const int nwaves = ((int)gridDim.x - P1_BLOCKS) * (FAT_THREADS >> 6);
    const int m    = lane & 15;
    const int quad = lane >> 4;

    frag_ab Bf[4][4];
#pragma unroll
    for (int kk = 0; kk < 4; ++kk) {
#pragma unroll
        for (int nt = 0; nt < 4; ++nt) {
            const float* wp = W + (size_t)(nt * 16 + m) * D_IN + kk * 32 + quad * 8;
            const float4 w0 = *(const float4*)wp;
            const float4 w1 = *(const float4*)(wp + 4);
            frag_ab f;
            f[0] = f2bf(w0.x); f[1] = f2bf(w0.y); f[2] = f2bf(w0.z); f[3] = f2bf(w0.w);
            f[4] = f2bf(w1.x); f[5] = f2bf(w1.y); f[6] = f2bf(w1.z); f[7] = f2bf(w1.w);
            Bf[kk][nt] = f;
        }
    }
    float bb[4];
#pragma unroll
    for (int nt = 0; nt < 4; ++nt) bb[nt] = bvec[nt * 16 + m];

    const int ntiles = (n_nodes + 15) / 16;
    for (int tile = wid; tile < ntiles; tile += nwaves) {
        const int node_base = tile * 16;
        int arow = node_base + m;
        if (arow > n_nodes - 1) arow = n_nodes - 1;

        float4 xv[8];
        const float* xr = x + (size_t)arow * D_IN + quad * 8;
#pragma unroll
        for (int kk = 0; kk < 4; ++kk) {
            xv[2 * kk]     = *(const float4*)(xr + kk * 32);
            xv[2 * kk + 1] = *(const float4*)(xr + kk * 32 + 4);
        }

        frag_cd acc[4];
#pragma unroll
        for (int nt = 0; nt < 4; ++nt) {
            acc[nt][0] = bb[nt]; acc[nt][1] = bb[nt];
            acc[nt][2] = bb[nt]; acc[nt][3] = bb[nt];
        }
#pragma unroll
        for (int kk = 0; kk < 4; ++kk) {
            const float4 x0 = xv[2 * kk], x1 = xv[2 * kk + 1];
            frag_ab A;
            A[0] = f2bf(x0.x); A[1] = f2bf(x0.y); A[2] = f2bf(x0.z); A[3] = f2bf(x0.w);
            A[4] = f2bf(x1.x); A[5] = f2bf(x1.y); A[6] = f2bf(x1.z); A[7] = f2bf(x1.w);
#pragma unroll
            for (int nt = 0; nt < 4; ++nt)
                acc[nt] = __builtin_amdgcn_mfma_f32_16x16x32_bf16(A, Bf[kk][nt],
                                                                  acc[nt], 0, 0, 0);
        }
#pragma unroll
        for (int nt = 0; nt < 4; ++nt) {
#pragma unroll
            for (int r = 0; r < 4; ++r) {
                const int node = node_base + quad * 4 + r;
                if (node < n_nodes)
                    h[(size_t)node * D_OUT + nt * 16 + m] =
                        (unsigned short)f2bf(acc[nt][r]);
            }
        }
    }
}

// ---------------------------------------------------------------------------
// Fused bucket-build + gather, now EXACT (no downstream overflow kernel).
// Block = (bin, slice of 64 nodes). ovfA records feed the same lbuck path
// (deg + contribution); entries beyond CAP stream into facc (LDS f32,
// on-CU atomics, zero work when empty). Gather: wave per node, quarter-wave
// per bucket entry, 4-way-unrolled uint2 h loads for MLP, shfl_xor reduce,
// facc fold, fused mean. Each block owns its 64 out rows -> no global atomics.
// ---------------------------------------------------------------------------
__global__ __launch_bounds__(FAT_THREADS)
void bin_gather_kernel(const unsigned* __restrict__ scratch,
                       const int* __restrict__ cursor,
                       const uint2* __restrict__ h64,
                       int* __restrict__ deg,
                       const unsigned* __restrict__ ovfA_list,
                       const int* __restrict__ ovfA_cnt, int ovfA_cap,
                       float* __restrict__ out, int n_nodes) {
    __shared__ int ldeg[64];
    __shared__ unsigned short lbuck[64 * CAP];   // 8 KB
    __shared__ float facc[64 * D_OUT];           // 16 KB overflow accumulator
    const int g     = (int)blockIdx.x;
    const int bin   = g >> SPLIT_SHIFT;
    const int slice = g & (SPLIT - 1);
    const int node0 = (bin << BIN_SHIFT) + (slice << 6);
    const int tid   = (int)threadIdx.x;

    int cnt = cursor[bin * 16]; if (cnt > BIN_CAP) cnt = BIN_CAP;

    if (tid < 64) ldeg[tid] = 0;
    for (int i = tid; i < 64 * D_OUT; i += FAT_THREADS) facc[i] = 0.f;
    __syncthreads();

    // scan the bin's records, keep rows in [slice*64, slice*64+64)
    for (int i = tid; i < cnt; i += FAT_THREADS) {
        const unsigned rec = scratch[(size_t)bin * BIN_CAP + i];
        const int rl = (int)(rec & 255u);
        if ((rl >> 6) == slice) {
            const int r6 = rl & 63;
            const int s = atomicAdd(&ldeg[r6], 1);
            if (s < CAP) lbuck[(r6 << 6) + s] = (unsigned short)(rec >> 8);
            else         facc_accum(facc, h64, r6, (int)(rec >> 8));
        }
    }
    // pass1-overflow edges: same path (deg + contribution), fast path = 0 work
    int cA = *ovfA_cnt; if (cA > ovfA_cap) cA = ovfA_cap;
    if (cA > 0) {
        const int gslice = node0 >> 6;
        for (int i = tid; i < cA; i += FAT_THREADS) {
            const unsigned rec = ovfA_list[i];
            const int r = (int)(rec & 0xFFFFu);
            if ((r >> 6) == gslice) {
                const int r6 = r & 63;
                const int c = (int)(rec >> 16);
                const int s = atomicAdd(&ldeg[r6], 1);
                if (s < CAP) lbuck[(r6 << 6) + s] = (unsigned short)c;
                else         facc_accum(facc, h64, r6, c);
            }
        }
    }
    __syncthreads();

    if (tid < 64 && node0 + tid < n_nodes) deg[node0 + tid] = ldeg[tid];

    // gather straight from LDS buckets
    const int lane = tid & 63;
    const int q = lane >> 4;
    const int j = lane & 15;
    const int w = tid >> 6;   // wave 0..7

    for (int r6 = w; r6 < 64; r6 += 8) {
        const int node = node0 + r6;
        if (node >= n_nodes) continue;
        const int d = ldeg[r6];
        const int dc = d < CAP ? d : CAP;
        const int ngr = (dc + 3) >> 2;
        const unsigned short* brow = &lbuck[r6 << 6];

        float a0 = 0.f, a1 = 0.f, a2 = 0.f, a3 = 0.f;
        float b0 = 0.f, b1 = 0.f, b2 = 0.f, b3 = 0.f;
        int g2 = 0;
        for (; g2 + 4 <= ngr; g2 += 4) {          // 4 loads in flight (MLP)
            const int i0 = (int)brow[4 * g2 + q];
            const int i1 = (int)brow[4 * g2 + 4 + q];
            const int i2 = (int)brow[4 * g2 + 8 + q];
            const int i3 = (int)brow[4 * g2 + 12 + q];
            uint2 w0 = h64[(size_t)i0 * 16 + j];
            uint2 w1 = h64[(size_t)i1 * 16 + j];
            uint2 w2 = h64[(size_t)i2 * 16 + j];
            uint2 w3 = h64[(size_t)i3 * 16 + j];
            if (4 * g2 + 12 + q >= dc) { w3.x = 0u; w3.y = 0u; }
            a0 += bflo(w0.x); a1 += bfhi(w0.x); a2 += bflo(w0.y); a3 += bfhi(w0.y);
            b0 += bflo(w1.x); b1 += bfhi(w1.x); b2 += bflo(w1.y); b3 += bfhi(w1.y);
            a0 += bflo(w2.x); a1 += bfhi(w2.x); a2 += bflo(w2.y); a3 += bfhi(w2.y);
            b0 += bflo(w3.x); b1 += bfhi(w3.x); b2 += bflo(w3.y); b3 += bfhi(w3.y);
        }
        for (; g2 + 2 <= ngr; g2 += 2) {
            const int iA = (int)brow[4 * g2 + q];
            const int iB = (int)brow[4 * g2 + 4 + q];
            uint2 wA = h64[(size_t)iA * 16 + j];
            uint2 wB = h64[(size_t)iB * 16 + j];
            if (4 * g2 + q >= dc)     { wA.x = 0u; wA.y = 0u; }
            if (4 * g2 + 4 + q >= dc) { wB.x = 0u; wB.y = 0u; }
            a0 += bflo(wA.x); a1 += bfhi(wA.x); a2 += bflo(wA.y); a3 += bfhi(wA.y);
            b0 += bflo(wB.x); b1 += bfhi(wB.x); b2 += bflo(wB.y); b3 += bfhi(wB.y);
        }
        for (; g2 < ngr; ++g2) {
            const int iA = (int)brow[4 * g2 + q];
            uint2 wA = h64[(size_t)iA * 16 + j];
            if (4 * g2 + q >= dc) { wA.x = 0u; wA.y = 0u; }
            a0 += bflo(wA.x); a1 += bfhi(wA.x); a2 += bflo(wA.y); a3 += bfhi(wA.y);
        }
        a0 += b0; a1 += b1; a2 += b2; a3 += b3;
        a0 += __shfl_xor(a0, 16); a0 += __shfl_xor(a0, 32);
        a1 += __shfl_xor(a1, 16); a1 += __shfl_xor(a1, 32);
        a2 += __shfl_xor(a2, 16); a2 += __shfl_xor(a2, 32);
        a3 += __shfl_xor(a3, 16); a3 += __shfl_xor(a3, 32);
        if (q == 0) {
            const float* fa = &facc[(r6 << 6) + j * 4];
            const float inv = 1.0f / fmaxf((float)d, 1.0f);
            float4 o;
            o.x = (a0 + fa[0]) * inv; o.y = (a1 + fa[1]) * inv;
            o.z = (a2 + fa[2]) * inv; o.w = (a3 + fa[3]) * inv;
            *(float4*)(out + (size_t)node * D_OUT + j * 4) = o;
        }
    }
}

// ---------------------------------------------------------------------------
// Last-resort path (ws too small or n_nodes > 65536): fp32 h + atomic scatter.
// ---------------------------------------------------------------------------
__global__ void proj_only_kernel(const float* __restrict__ x,
                                 const float* __restrict__ W,
                                 const float* __restrict__ bvec,
                                 float* __restrict__ h, int n_nodes) {
    const int lane = (int)threadIdx.x & 63;
    const int wave = (int)((blockIdx.x * blockDim.x + threadIdx.x) >> 6);
    const int nwaves = (int)((gridDim.x * blockDim.x) >> 6);
    const float bias = bvec[lane];
    for (int node = wave; node < n_nodes; node += nwaves) {
        const float* xr = &x[(size_t)node * D_IN];
        float acc = bias;
#pragma unroll
        for (int k = 0; k < D_IN; ++k) acc += xr[k] * W[lane * D_IN + k];
        h[(size_t)node * D_OUT + lane] = acc;
    }
}

__global__ void scatter_kernel(const float* __restrict__ h,
                               const int* __restrict__ row,
                               const int* __restrict__ col,
                               float* __restrict__ out,
                               int* __restrict__ deg,
                               long long n_tasks) {
    long long t = (long long)blockIdx.x * blockDim.x + threadIdx.x;
    const long long stride = (long long)gridDim.x * blockDim.x;
    for (; t < n_tasks; t += stride) {
        const int e = (int)(t >> 6);
        const int c = (int)(t & 63);
        atomicAdd(&out[(size_t)row[e] * D_OUT + c], h[(size_t)col[e] * D_OUT + c]);
        if (c == 0) atomicAdd(&deg[row[e]], 1);
    }
}

__global__ void div_kernel(float* __restrict__ out,
                           const int* __restrict__ deg, int n_total) {
    int t = blockIdx.x * blockDim.x + threadIdx.x;
    if (t < n_total) {
        out[t] *= 1.0f / fmaxf((float)deg[t >> 6], 1.0f);
    }
}

extern "C" void kernel_launch(void* const* d_in, const int* in_sizes, int n_in,
                              void* d_out, int out_size, void* d_ws, size_t ws_size,
                              hipStream_t stream) {
    const float* x   = (const float*)d_in[0];
    const float* W   = (const float*)d_in[1];
    const float* b   = (const float*)d_in[2];
    const int*   row = (const int*)d_in[3];
    const int*   col = (const int*)d_in[4];
    float* out = (float*)d_out;

    const int n_nodes = in_sizes[0] / D_IN;
    const int n_edges = in_sizes[3];
    const int n_bins  = (n_nodes + 255) >> BIN_SHIFT;

    // Workspace: h(bf16) | deg | [ovfA_cnt pad 256B] | cursor(padded)
    //            | ovfA_list | scratch
    char* p = (char*)d_ws;
    unsigned short* h = (unsigned short*)p;
    p += (size_t)n_nodes * D_OUT * sizeof(unsigned short);
    int* deg = (int*)p;            p += (size_t)n_nodes * sizeof(int);
    int* ovf_cnts = (int*)p;       p += 256;                       // [0]=A
    int* cursor = (int*)p;         p += (size_t)MAX_BINS * 16 * sizeof(int);
    unsigned* ovfA_list = (unsigned*)p;  p += (size_t)n_edges * sizeof(unsigned);
    unsigned* scratch = (unsigned*)p;
    p += (size_t)n_bins * BIN_CAP * sizeof(unsigned);
    const size_t needed = (size_t)(p - (char*)d_ws);

    if (ws_size >= needed && n_nodes <= MAX_USHORT_NODES) {
        // zero: ovfA counter + padded cursor (contiguous)
        hipMemsetAsync(ovf_cnts, 0, 256 + (size_t)MAX_BINS * 16 * sizeof(int),
                       stream);

        // 1) projection || binpass1 (independent; complementary pipes)
        const int ntiles = (n_nodes + 15) / 16;
        int proj_blocks = (ntiles + 15) / 16;     // 8 waves/block, 2 tiles/wave
        if (proj_blocks < 1) proj_blocks = 1;
        proj_bin1_kernel<<<P1_BLOCKS + proj_blocks, FAT_THREADS, 0, stream>>>(
            x, W, b, h, row, col, scratch, cursor, &ovf_cnts[0], ovfA_list,
            n_edges, n_nodes, n_edges, n_bins);

        // 2) fused bucket-build + gather, exact (no downstream kernel)
        bin_gather_kernel<<<n_bins * SPLIT, FAT_THREADS, 0, stream>>>(
            scratch, cursor, (const uint2*)h, deg, ovfA_list, &ovf_cnts[0],
            n_edges, out, n_nodes);
    } else {
        // last resort: fp32 h + atomic scatter
        float* hf = (float*)d_ws;
        int* degf = (int*)((char*)d_ws + (size_t)n_nodes * D_OUT * sizeof(float));
        hipMemsetAsync(out, 0, (size_t)out_size * sizeof(float), stream);
        hipMemsetAsync(degf, 0, (size_t)n_nodes * sizeof(int), stream);
        proj_only_kernel<<<1024, 256, 0, stream>>>(x, W, b, hf, n_nodes);
        const long long n_tasks = (long long)n_edges * D_OUT;
        scatter_kernel<<<16384, 256, 0, stream>>>(hf, row, col, out, degf, n_tasks);
        const int n_total = n_nodes * D_OUT;
        div_kernel<<<(n_total + 255) / 256, 256, 0, stream>>>(out, degf, n_total);
    }
}